// Round 3
// baseline (308.921 us; speedup 1.0000x reference)
//
#include <hip/hip_runtime.h>
#include <hip/hip_bf16.h>

typedef __bf16 bf16x8 __attribute__((ext_vector_type(8)));
typedef float floatx4 __attribute__((ext_vector_type(4)));

// async global->LDS, 16B per lane; LDS dst = wave-uniform base + lane*16
static __device__ __forceinline__ void async_cp16(const __bf16* g, __bf16* l) {
    typedef const __attribute__((address_space(1))) unsigned int gu32;
    typedef __attribute__((address_space(3))) unsigned int lu32;
    __builtin_amdgcn_global_load_lds((gu32*)g, (lu32*)l, 16, 0, 0);
}

// ---------------------------------------------------------------------------
// 64x64 transpose tile, fp32 src -> bf16 dst. Vectorized global I/O both sides.
// src[R][C], dst[C][R]; tile origin (r0, c0).
// ---------------------------------------------------------------------------
static __device__ __forceinline__ void tile64_f32(
    const float* __restrict__ src, __bf16* __restrict__ dst,
    int R, int C, int r0, int c0, int tid, __bf16* t /* [64*72] */)
{
    {
        const int r = tid >> 2, cq = (tid & 3) * 16;
        const float* p = src + (size_t)(r0 + r) * C + c0 + cq;
        float4 f0 = *(const float4*)(p);
        float4 f1 = *(const float4*)(p + 4);
        float4 f2 = *(const float4*)(p + 8);
        float4 f3 = *(const float4*)(p + 12);
        __bf16 v[16] = {
            (__bf16)f0.x, (__bf16)f0.y, (__bf16)f0.z, (__bf16)f0.w,
            (__bf16)f1.x, (__bf16)f1.y, (__bf16)f1.z, (__bf16)f1.w,
            (__bf16)f2.x, (__bf16)f2.y, (__bf16)f2.z, (__bf16)f2.w,
            (__bf16)f3.x, (__bf16)f3.y, (__bf16)f3.z, (__bf16)f3.w };
        #pragma unroll
        for (int e = 0; e < 16; ++e) t[(cq + e) * 72 + r] = v[e];
    }
    __syncthreads();
    {
        const int c = tid >> 2, rq = (tid & 3) * 16;
        uint4 u0 = *(const uint4*)(&t[c * 72 + rq]);
        uint4 u1 = *(const uint4*)(&t[c * 72 + rq + 8]);
        __bf16* q = dst + (size_t)(c0 + c) * R + r0 + rq;
        *(uint4*)(q)     = u0;
        *(uint4*)(q + 8) = u1;
    }
}

// same, bf16 src -> bf16 dst (for V transpose); src stride lds_src, dst stride R
static __device__ __forceinline__ void tile64_b16(
    const __bf16* __restrict__ src, __bf16* __restrict__ dst,
    int src_ld, int dst_ld, int tid, __bf16* t /* [64*72] */)
{
    {
        const int r = tid >> 2, cq = (tid & 3) * 16;
        const __bf16* p = src + (size_t)r * src_ld + cq;
        union { uint4 u; __bf16 b[8]; } a0, a1;
        a0.u = *(const uint4*)(p);
        a1.u = *(const uint4*)(p + 8);
        #pragma unroll
        for (int e = 0; e < 8; ++e) {
            t[(cq + e) * 72 + r]     = a0.b[e];
            t[(cq + 8 + e) * 72 + r] = a1.b[e];
        }
    }
    __syncthreads();
    {
        const int c = tid >> 2, rq = (tid & 3) * 16;
        uint4 u0 = *(const uint4*)(&t[c * 72 + rq]);
        uint4 u1 = *(const uint4*)(&t[c * 72 + rq + 8]);
        __bf16* q = dst + (size_t)c * dst_ld + rq;
        *(uint4*)(q)     = u0;
        *(uint4*)(q + 8) = u1;
    }
}

// ---------------------------------------------------------------------------
// Fused prep: [0,2048) Wq-T; [2048,2560) Wk-T; [2560,3072) Wv-T;
// [3072,5120) x convert. 256 threads.
// ---------------------------------------------------------------------------
__global__ __launch_bounds__(256) void prep_kernel(
    const float* __restrict__ x,  __bf16* __restrict__ xb,
    const float* __restrict__ Wq, const float* __restrict__ Wk,
    const float* __restrict__ Wv, __bf16* __restrict__ Wt)
{
    __shared__ __bf16 t[64 * 72];
    const int bk  = blockIdx.x;
    const int tid = threadIdx.x;

    if (bk < 2048) {            // Wq [2048][4096] -> Wt[0..4096) rows
        int ct = bk & 63, rt = bk >> 6;
        tile64_f32(Wq, Wt, 2048, 4096, rt * 64, ct * 64, tid, t);
    } else if (bk < 2560) {     // Wk [2048][1024] -> Wt[4096..5120)
        int idx = bk - 2048, ct = idx & 15, rt = idx >> 4;
        tile64_f32(Wk, Wt + (size_t)4096 * 2048, 2048, 1024, rt * 64, ct * 64, tid, t);
    } else if (bk < 3072) {     // Wv [2048][1024] -> Wt[5120..6144)
        int idx = bk - 2560, ct = idx & 15, rt = idx >> 4;
        tile64_f32(Wv, Wt + (size_t)5120 * 2048, 2048, 1024, rt * 64, ct * 64, tid, t);
    } else {                    // x convert
        int idx = (bk - 3072) * 256 + tid;
        const float* p = x + (size_t)idx * 8;
        float4 f0 = *(const float4*)p;
        float4 f1 = *(const float4*)(p + 4);
        union { uint4 u; __bf16 b[8]; } o;
        o.b[0] = (__bf16)f0.x; o.b[1] = (__bf16)f0.y; o.b[2] = (__bf16)f0.z; o.b[3] = (__bf16)f0.w;
        o.b[4] = (__bf16)f1.x; o.b[5] = (__bf16)f1.y; o.b[6] = (__bf16)f1.z; o.b[7] = (__bf16)f1.w;
        *(uint4*)(xb + (size_t)idx * 8) = o.u;
    }
}

// ---------------------------------------------------------------------------
// Fused RoPE + V-transpose + Wo-transpose (post-GEMM1).
// [0,2560): rope; [2560,3072): vtrans; [3072,5120): Wo-T.
// ---------------------------------------------------------------------------
__global__ __launch_bounds__(256) void rope_vtrans_wot_kernel(
    __bf16* __restrict__ qkv, __bf16* __restrict__ vt,
    const float* __restrict__ Wo, __bf16* __restrict__ WoT)
{
    __shared__ __bf16 t[64 * 72];
    const int bk  = blockIdx.x;
    const int tid = threadIdx.x;

    if (bk < 2560) {
        int idx  = bk * 256 + tid;
        int part = idx & 7;
        int tt   = idx >> 3;
        int head = tt % 40;
        int row  = tt / 40;
        int n    = row & 1023;
        int col0 = (head < 32) ? head * 128 : 4096 + (head - 32) * 128;
        size_t base = (size_t)row * 6144 + col0 + part * 8;

        union { uint4 u; __bf16 b[8]; } x1, x2, o1, o2;
        x1.u = *(const uint4*)(qkv + base);
        x2.u = *(const uint4*)(qkv + base + 64);
        #pragma unroll
        for (int e = 0; e < 8; ++e) {
            int j = part * 8 + e;
            float inv_freq = exp2f(-(float)j * 0.20762050593046015f); // log2(1e4)/64
            float ang = (float)n * inv_freq;
            float sv, cv;
            __sincosf(ang, &sv, &cv);
            float a = (float)x1.b[e], b2 = (float)x2.b[e];
            o1.b[e] = (__bf16)(a * cv - b2 * sv);
            o2.b[e] = (__bf16)(a * sv + b2 * cv);
        }
        *(uint4*)(qkv + base)      = o1.u;
        *(uint4*)(qkv + base + 64) = o2.u;
    } else if (bk < 3072) {      // V cols of qkv -> vt[bh][128][1024]
        int idx = bk - 2560;     // 512: bh = idx>>5, rem 32 = 16 ktiles x 2 vtiles
        int bh = idx >> 5, rem = idx & 31;
        int k0 = (rem >> 1) * 64, v0 = (rem & 1) * 64;
        int b = bh >> 3, h = bh & 7;
        const __bf16* src = qkv + (size_t)(b * 1024 + k0) * 6144 + 5120 + h * 128 + v0;
        __bf16* dst = vt + ((size_t)bh * 128 + v0) * 1024 + k0;
        tile64_b16(src, dst, 6144, 1024, tid, t);
    } else {                     // Wo [4096][2048] -> WoT [2048][4096]
        int idx = bk - 3072;     // 2048: 32 ctiles x 64 rtiles
        int ct = idx & 31, rt = idx >> 5;
        tile64_f32(Wo, WoT, 4096, 2048, rt * 64, ct * 64, tid, t);
    }
}

// ---------------------------------------------------------------------------
// GEMM: C[z][M][N] = A[M][koff:] * Bt[N][koff:]^T, bf16.
// 256x256 tile, BK=64, 512 threads (8 waves, 2Mx4N).
// Software-pipelined K-loop: 2 barriers/K-tile, counted lgkmcnt, deferred
// second-half MFMA hides next tile's ds_reads. T2 swizzle + T5 setprio.
//
// Per K-tile t (buf c = t&1), per wave:
//   issue af0(t) [8 ds_read]           | M2(t-1): af1 x bf  [32 MFMA]
//   lgkmcnt(0)  (hidden under M2)
//   issue bf(t) [8] + af1(t) [8]
//   lgkmcnt(8)  (bf landed, af1 in flight)
//   M1(t): af0 x bf [32 MFMA]  (hides af1 drain)
//   lgkmcnt(0)
//   barrier  -- all waves done reading buf c
//   DMA tile t+2 -> buf c [8 cp16]
//   vmcnt(8)  -- tile t+1 landed, t+2 stays in flight
//   barrier  -- tile t+1 visible
// Deferred M2 uses only registers (af1,bf of tile t) -> safe across barriers;
// next iter's reads (af0) don't touch them -> no double buffering needed.
// ---------------------------------------------------------------------------
__global__ __launch_bounds__(512) void gemm_bt(
    const __bf16* __restrict__ A,
    const __bf16* __restrict__ Bt,
    __bf16* __restrict__ C,
    int M, int lda, int ldb, int ldc,
    int kc_base, int kc_extra)
{
    __shared__ __bf16 As[2][256 * 64];
    __shared__ __bf16 Bs[2][256 * 64];

    const int tid  = threadIdx.x;
    const int wave = tid >> 6;
    const int lane = tid & 63;
    const int quad = lane >> 4;
    const int l15  = lane & 15;
    const int wr   = wave >> 2;        // 0..1  (M half)
    const int wc   = wave & 3;         // 0..3  (N quarter)

    const int bm = blockIdx.y * 256;
    const int bn = blockIdx.x * 256;
    const int z  = blockIdx.z;
    const int Kc = kc_base + ((z == (int)gridDim.z - 1) ? kc_extra : 0);
    const int NT = Kc >> 6;

    A  += (size_t)z * kc_base;
    Bt += (size_t)z * kc_base;
    C  += (size_t)z * M * ldc;

    floatx4 acc[32];
    #pragma unroll
    for (int i = 0; i < 32; ++i) acc[i] = floatx4{0.f, 0.f, 0.f, 0.f};

    // staging source (pre-swizzled global so linear DMA == swizzled layout)
    const int sr = lane >> 3;                  // 0..7 row-in-8
    const int sc = ((lane & 7) ^ sr) * 8;      // swizzled k-chunk
    const __bf16* a0 = A  + (size_t)(bm + wave * 8 + sr) * lda + sc;
    const __bf16* b0 = Bt + (size_t)(bn + wave * 8 + sr) * ldb + sc;
    const int ldsw = wave * 512;               // (wave*8)*64 elems, wave-uniform

    // read-side bases: LDS[r][ch] = glob[r][ch ^ (r&7)], r&7 == l15&7
    const int arow = (wr * 128 + l15) * 64;
    const int brow = (wc * 64  + l15) * 64;
    const int cx0  = ((0 + quad) ^ (l15 & 7)) * 8;   // ko=0 chunk
    const int cx1  = ((4 + quad) ^ (l15 & 7)) * 8;   // ko=1 chunk

    // ---- prologue: tiles 0 and 1, A+B, fully staged ----
    #pragma unroll
    for (int q = 0; q < 4; ++q)
        async_cp16(a0 + (size_t)(q * 64) * lda, (__bf16*)&As[0][q * 4096 + ldsw]);
    #pragma unroll
    for (int q = 0; q < 4; ++q)
        async_cp16(b0 + (size_t)(q * 64) * ldb, (__bf16*)&Bs[0][q * 4096 + ldsw]);
    if (NT > 1) {
        #pragma unroll
        for (int q = 0; q < 4; ++q)
            async_cp16(a0 + (size_t)(q * 64) * lda + 64, (__bf16*)&As[1][q * 4096 + ldsw]);
        #pragma unroll
        for (int q = 0; q < 4; ++q)
            async_cp16(b0 + (size_t)(q * 64) * ldb + 64, (__bf16*)&Bs[1][q * 4096 + ldsw]);
        asm volatile("s_waitcnt vmcnt(8)" ::: "memory");   // tile 0 landed
    } else {
        asm volatile("s_waitcnt vmcnt(0)" ::: "memory");
    }
    __builtin_amdgcn_s_barrier();
    __builtin_amdgcn_sched_barrier(0);

    bf16x8 af1[4][2], bf[4][2];   // loop-carried: consumed by deferred M2

    for (int t = 0; t < NT; ++t) {
        const int cur = t & 1;
        const __bf16* Ac = As[cur];
        const __bf16* Bc = Bs[cur];
        __bf16* An = (__bf16*)As[cur];     // tile t+2 destination (rotation)
        __bf16* Bn = (__bf16*)Bs[cur];

        // -- issue af0(t) reads (8 ds_read_b128) --
        bf16x8 af0[4][2];
        #pragma unroll
        for (int tt = 0; tt < 4; ++tt) {
            af0[tt][0] = *(const bf16x8*)(&Ac[arow + tt * 1024 + cx0]);
            af0[tt][1] = *(const bf16x8*)(&Ac[arow + tt * 1024 + cx1]);
        }
        __builtin_amdgcn_sched_barrier(0);

        // -- deferred M2(t-1): af1 x bf, hides af0 drain --
        if (t) {
            __builtin_amdgcn_s_setprio(1);
            #pragma unroll
            for (int ko = 0; ko < 2; ++ko)
                #pragma unroll
                for (int tt = 0; tt < 4; ++tt)
                    #pragma unroll
                    for (int uu = 0; uu < 4; ++uu)
                        acc[(4 + tt) * 4 + uu] = __builtin_amdgcn_mfma_f32_16x16x32_bf16(
                            af1[tt][ko], bf[uu][ko], acc[(4 + tt) * 4 + uu], 0, 0, 0);
            __builtin_amdgcn_s_setprio(0);
        }
        __builtin_amdgcn_sched_barrier(0);
        asm volatile("s_waitcnt lgkmcnt(0)" ::: "memory");   // af0 ready
        __builtin_amdgcn_sched_barrier(0);

        // -- issue bf(t) [8 reads, oldest] then af1(t) [8 reads] --
        #pragma unroll
        for (int uu = 0; uu < 4; ++uu) {
            bf[uu][0] = *(const bf16x8*)(&Bc[brow + uu * 1024 + cx0]);
            bf[uu][1] = *(const bf16x8*)(&Bc[brow + uu * 1024 + cx1]);
        }
        #pragma unroll
        for (int tt = 0; tt < 4; ++tt) {
            af1[tt][0] = *(const bf16x8*)(&Ac[arow + (4 + tt) * 1024 + cx0]);
            af1[tt][1] = *(const bf16x8*)(&Ac[arow + (4 + tt) * 1024 + cx1]);
        }
        __builtin_amdgcn_sched_barrier(0);
        asm volatile("s_waitcnt lgkmcnt(8)" ::: "memory");   // bf landed, af1 in flight
        __builtin_amdgcn_sched_barrier(0);

        // -- M1(t): af0 x bf, hides af1 drain --
        __builtin_amdgcn_s_setprio(1);
        #pragma unroll
        for (int ko = 0; ko < 2; ++ko)
            #pragma unroll
            for (int tt = 0; tt < 4; ++tt)
                #pragma unroll
                for (int uu = 0; uu < 4; ++uu)
                    acc[tt * 4 + uu] = __builtin_amdgcn_mfma_f32_16x16x32_bf16(
                        af0[tt][ko], bf[uu][ko], acc[tt * 4 + uu], 0, 0, 0);
        __builtin_amdgcn_s_setprio(0);
        __builtin_amdgcn_sched_barrier(0);
        asm volatile("s_waitcnt lgkmcnt(0)" ::: "memory");   // af1 ready (hidden)
        __builtin_amdgcn_sched_barrier(0);

        // -- all waves done reading buf cur -> safe to overwrite --
        __builtin_amdgcn_s_barrier();
        if (t + 2 < NT) {
            #pragma unroll
            for (int q = 0; q < 4; ++q)
                async_cp16(a0 + (size_t)(q * 64) * lda + (t + 2) * 64,
                           An + q * 4096 + ldsw);
            #pragma unroll
            for (int q = 0; q < 4; ++q)
                async_cp16(b0 + (size_t)(q * 64) * ldb + (t + 2) * 64,
                           Bn + q * 4096 + ldsw);
            asm volatile("s_waitcnt vmcnt(8)" ::: "memory");   // tile t+1 landed
        } else {
            asm volatile("s_waitcnt vmcnt(0)" ::: "memory");   // tail drain
        }
        __builtin_amdgcn_s_barrier();                          // tile t+1 visible
        __builtin_amdgcn_sched_barrier(0);
        // M2(t) deferred to next iteration (registers only)
    }

    // -- final deferred M2(NT-1) --
    __builtin_amdgcn_s_setprio(1);
    #pragma unroll
    for (int ko = 0; ko < 2; ++ko)
        #pragma unroll
        for (int tt = 0; tt < 4; ++tt)
            #pragma unroll
            for (int uu = 0; uu < 4; ++uu)
                acc[(4 + tt) * 4 + uu] = __builtin_amdgcn_mfma_f32_16x16x32_bf16(
                    af1[tt][ko], bf[uu][ko], acc[(4 + tt) * 4 + uu], 0, 0, 0);
    __builtin_amdgcn_s_setprio(0);

    // ---- epilogue: C write ----
    #pragma unroll
    for (int tt = 0; tt < 8; ++tt)
        #pragma unroll
        for (int uu = 0; uu < 4; ++uu) {
            const int row = bm + wr * 128 + tt * 16 + quad * 4;
            const int col = bn + wc * 64 + uu * 16 + l15;
            #pragma unroll
            for (int r = 0; r < 4; ++r)
                C[(size_t)(row + r) * ldc + col] = (__bf16)acc[tt * 4 + uu][r];
        }
}

// ---------------------------------------------------------------------------
// Split-K reduce: out = sum of 3 bf16 partials, fp32 out.
// ---------------------------------------------------------------------------
__global__ __launch_bounds__(256) void reduce_kernel(
    const __bf16* __restrict__ part, float* __restrict__ out)
{
    int idx = blockIdx.x * 256 + threadIdx.x;
    const size_t S = (size_t)2048 * 2048;
    union { uint4 u; __bf16 b[8]; } p0, p1, p2;
    p0.u = *(const uint4*)(part + (size_t)idx * 8);
    p1.u = *(const uint4*)(part + S + (size_t)idx * 8);
    p2.u = *(const uint4*)(part + 2 * S + (size_t)idx * 8);
    float4 o0, o1;
    o0.x = (float)p0.b[0] + (float)p1.b[0] + (float)p2.b[0];
    o0.y = (float)p0.b[1] + (float)p1.b[1] + (float)p2.b[1];
    o0.z = (float)p0.b[2] + (float)p1.b[2] + (float)p2.b[2];
    o0.w = (float)p0.b[3] + (float)p1.b[3] + (float)p2.b[3];
    o1.x = (float)p0.b[4] + (float)p1.b[4] + (float)p2.b[4];
    o1.y = (float)p0.b[5] + (float)p1.b[5] + (float)p2.b[5];
    o1.z = (float)p0.b[6] + (float)p1.b[6] + (float)p2.b[6];
    o1.w = (float)p0.b[7] + (float)p1.b[7] + (float)p2.b[7];
    *(float4*)(out + (size_t)idx * 8)     = o0;
    *(float4*)(out + (size_t)idx * 8 + 4) = o1;
}

// ---------------------------------------------------------------------------
// Causal flash attention (R5 structure: balanced pairing, max-free softmax,
// swizzled DMA staging).
// ---------------------------------------------------------------------------
__global__ __launch_bounds__(512, 2) void attn_kernel(
    const __bf16* __restrict__ qkv,
    const __bf16* __restrict__ vt,
    __bf16* __restrict__ ao)
{
    const int PS_LD = 72;
    __shared__ __bf16 Ks[64 * 128];      // [key][kdim], swizzled
    __shared__ __bf16 Vs[128 * 64];      // [vdim][key], swizzled
    __shared__ __bf16 Ps[8][16 * PS_LD]; // per-wave [qrow][key], padded

    const int tid  = threadIdx.x;
    const int wave = tid >> 6;
    const int lane = tid & 63;
    const int quad = lane >> 4;
    const int l15  = lane & 15;
    const int i    = wave >> 1;
    const int rt   = wave & 1;

    const int pair = blockIdx.x;
    const int bh   = blockIdx.y;
    const int b    = bh >> 3, h = bh & 7;
    const __bf16* vtb = vt + (size_t)bh * 128 * 1024;

    const int keyA = wave * 8 + (lane >> 4);
    const int keyB = keyA + 4;
    const int chA  = (lane & 15) ^ (keyA & 15);
    const int chB  = (lane & 15) ^ (keyB & 15);
    const __bf16* gK0 = qkv + (size_t)(b * 1024 + keyA) * 6144 + 4096 + h * 128 + chA * 8;
    const __bf16* gK1 = qkv + (size_t)(b * 1024 + keyB) * 6144 + 4096 + h * 128 + chB * 8;
    __bf16* lK0 = Ks + (wave * 8) * 128;
    __bf16* lK1 = Ks + (wave * 8 + 4) * 128;

    const int vdA = wave * 16 + (lane >> 3);
    const int vdB = vdA + 8;
    const int cvA = (lane & 7) ^ (vdA & 7);
    const int cvB = (lane & 7) ^ (vdB & 7);
    const __bf16* gV0 = vtb + (size_t)vdA * 1024 + cvA * 8;
    const __bf16* gV1 = vtb + (size_t)vdB * 1024 + cvB * 8;
    __bf16* lV0 = Vs + (wave * 16) * 64;
    __bf16* lV1 = Vs + (wave * 16 + 8) * 64;

    bf16x8 onesf;
    #pragma unroll
    for (int j = 0; j < 8; ++j) onesf[j] = (__bf16)1.0f;

    const float C2 = 0.12751898549f;   // (1/sqrt(128)) * log2(e)

    #pragma unroll
    for (int ph = 0; ph < 2; ++ph) {
        const int qt    = ph ? (31 - pair) : pair;
        const int qrow0 = qt * 32 + rt * 16;

        const __bf16* qp = qkv + (size_t)(b * 1024 + qrow0 + l15) * 6144 + (h * 4 + i) * 128;
        bf16x8 qf[4];
        #pragma unroll
        for (int c = 0; c < 4; ++c)
            qf[c] = *(const bf16x8*)(qp + c * 32 + quad * 8);

        floatx4 acc[8];
        #pragma unroll
        for (int u = 0; u < 8; ++u) acc[u] = floatx4{0.f, 0.f, 0.f, 0.f};
        floatx4 accl = floatx4{0.f, 0.f, 0.f, 0.f};

        const int ntiles = (qt >> 1) + 1;
        for (int t = 0; t < ntiles; ++t) {
            const int kt = t * 64;
            __syncthreads();
            async_cp16(gK0 + (size_t)kt * 6144, lK0);
            async_cp16(gK1 + (size_t)kt * 6144, lK1);
            async_cp16(gV0 + kt, lV0);
            async_cp16(gV1 + kt, lV1);
            __syncthreads();

            floatx4 s[4];
            #pragma unroll
            for (int ks = 0; ks < 4; ++ks) s[ks] = floatx4{0.f, 0.f, 0.f, 0.f};
            #pragma unroll
            for (int c = 0; c < 4; ++c) {
                #pragma unroll
                for (int ks = 0; ks < 4; ++ks) {
                    bf16x8 kf = *(const bf16x8*)(
                        &Ks[(ks * 16 + l15) * 128 + ((c * 4 + quad) ^ l15) * 8]);
                    s[ks] = __builtin_amdgcn_mfma_f32_16x16x32_bf16(qf[c], kf, s[ks], 0, 0, 0);
                }
            }

            #pragma unroll
            for (int r = 0; r < 4; ++r) {
                int qrow = qrow0 + quad * 4 + r;
                #pragma unroll
                for (int ks = 0; ks < 4; ++ks) {
                    int kc = kt + ks * 16 + l15;
                    float p = (kc <= qrow) ? exp2f(s[ks][r] * C2) : 0.0f;
                    Ps[wave][(quad * 4 + r) * PS_LD + ks * 16 + l15] = (__bf16)p;
                }
            }

            #pragma unroll
            for (int s2 = 0; s2 < 2; ++s2) {
                bf16x8 pa = *(const bf16x8*)(&Ps[wave][l15 * PS_LD + s2 * 32 + quad * 8]);
                accl = __builtin_amdgcn_mfma_f32_16x16x32_bf16(pa, onesf, accl, 0, 0, 0);
                #pragma unroll
                for (int u = 0; u < 8; ++u) {
                    bf16x8 vf = *(const bf16x8*)(
                        &Vs[(u * 16 + l15) * 64 + (((s2 * 4 + quad) ^ (l15 & 7))) * 8]);
                    acc[u] = __builtin_amdgcn_mfma_f32_16x16x32_bf16(pa, vf, acc[u], 0, 0, 0);
                }
            }
        }

        #pragma unroll
        for (int r = 0; r < 4; ++r) {
            float inv = 1.0f / accl[r];
            int row = qrow0 + quad * 4 + r;
            __bf16* op = ao + (size_t)(b * 1024 + row) * 4096 + (h * 4 + i) * 128;
            #pragma unroll
            for (int u = 0; u < 8; ++u)
                op[u * 16 + l15] = (__bf16)(acc[u][r] * inv);
        }
    }
}

// ---------------------------------------------------------------------------
extern "C" void kernel_launch(void* const* d_in, const int* in_sizes, int n_in,
                              void* d_out, int out_size, void* d_ws, size_t ws_size,
                              hipStream_t stream)
{
    const float* x  = (const float*)d_in[0];   // [2048][2048]
    const float* Wq = (const float*)d_in[1];   // [2048][4096]
    const float* Wk = (const float*)d_in[2];   // [2048][1024]
    const float* Wv = (const float*)d_in[3];   // [2048][1024]
    const float* Wo = (const float*)d_in[4];   // [4096][2048]
    float* out = (float*)d_out;                // [2048][2048]

    const size_t MB = 1024 * 1024;
    char* ws = (char*)d_ws;                    // 60 MB total
    __bf16* qkv  = (__bf16*)(ws);              // [2048][6144]    0-24  (dead after attn)
    __bf16* vtb  = (__bf16*)(ws + 24 * MB);    // [16][128][1024] 24-28 (dead after attn)
    __bf16* xb   = (__bf16*)(ws + 28 * MB);    // [2048][2048]    28-36 (dead after GEMM1)
    __bf16* Wt   = (__bf16*)(ws + 36 * MB);    // [6144][2048]    36-60 (dead after GEMM1)
    __bf16* WoT  = (__bf16*)(ws + 28 * MB);    // [2048][4096]    28-44 (post-GEMM1)
    __bf16* ao   = (__bf16*)(ws + 44 * MB);    // [2048][4096]    44-60 (post-GEMM1)
    __bf16* part = (__bf16*)(ws);              // [3][2048][2048] 0-24  (post-attn)

    // 1) prep: transpose Wq/Wk/Wv (vectorized 64x64 tiles) + convert x
    prep_kernel<<<5120, 256, 0, stream>>>(x, xb, Wq, Wk, Wv, Wt);
    // 2) fused QKV projection: qkv[2048][6144], 256x256 tiles, pipelined
    gemm_bt<<<dim3(24, 8), 512, 0, stream>>>(xb, Wt, qkv, 2048, 2048, 2048, 6144, 2048, 0);
    // 3) RoPE + V transpose + Wo transpose (WoT overwrites xb/Wt head)
    rope_vtrans_wot_kernel<<<5120, 256, 0, stream>>>(qkv, vtb, Wo, WoT);
    // 4) attention (writes ao; qkv/vtb dead afterwards)
    attn_kernel<<<dim3(16, 16), 512, 0, stream>>>(qkv, vtb, ao);
    // 5) output projection, split-K=3 (1344/1344/1408), partials in dead qkv
    gemm_bt<<<dim3(8, 8, 3), 512, 0, stream>>>(ao, WoT, part, 2048, 4096, 4096, 2048, 1344, 64);
    // 6) reduce partials -> fp32 out
    reduce_kernel<<<2048, 256, 0, stream>>>(part, out);
}

// Round 4
// 282.677 us; speedup vs baseline: 1.0928x; 1.0928x over previous
//
#include <hip/hip_runtime.h>
#include <hip/hip_bf16.h>

typedef __bf16 bf16x8 __attribute__((ext_vector_type(8)));
typedef float floatx4 __attribute__((ext_vector_type(4)));

// async global->LDS, 16B per lane; LDS dst = wave-uniform base + lane*16
static __device__ __forceinline__ void async_cp16(const __bf16* g, __bf16* l) {
    typedef const __attribute__((address_space(1))) unsigned int gu32;
    typedef __attribute__((address_space(3))) unsigned int lu32;
    __builtin_amdgcn_global_load_lds((gu32*)g, (lu32*)l, 16, 0, 0);
}

// ---------------------------------------------------------------------------
// 64x64 transpose tile, fp32 src -> bf16 dst. Vectorized global I/O both sides.
// src[R][C], dst[C][R]; tile origin (r0, c0).
// ---------------------------------------------------------------------------
static __device__ __forceinline__ void tile64_f32(
    const float* __restrict__ src, __bf16* __restrict__ dst,
    int R, int C, int r0, int c0, int tid, __bf16* t /* [64*72] */)
{
    {
        const int r = tid >> 2, cq = (tid & 3) * 16;
        const float* p = src + (size_t)(r0 + r) * C + c0 + cq;
        float4 f0 = *(const float4*)(p);
        float4 f1 = *(const float4*)(p + 4);
        float4 f2 = *(const float4*)(p + 8);
        float4 f3 = *(const float4*)(p + 12);
        __bf16 v[16] = {
            (__bf16)f0.x, (__bf16)f0.y, (__bf16)f0.z, (__bf16)f0.w,
            (__bf16)f1.x, (__bf16)f1.y, (__bf16)f1.z, (__bf16)f1.w,
            (__bf16)f2.x, (__bf16)f2.y, (__bf16)f2.z, (__bf16)f2.w,
            (__bf16)f3.x, (__bf16)f3.y, (__bf16)f3.z, (__bf16)f3.w };
        #pragma unroll
        for (int e = 0; e < 16; ++e) t[(cq + e) * 72 + r] = v[e];
    }
    __syncthreads();
    {
        const int c = tid >> 2, rq = (tid & 3) * 16;
        uint4 u0 = *(const uint4*)(&t[c * 72 + rq]);
        uint4 u1 = *(const uint4*)(&t[c * 72 + rq + 8]);
        __bf16* q = dst + (size_t)(c0 + c) * R + r0 + rq;
        *(uint4*)(q)     = u0;
        *(uint4*)(q + 8) = u1;
    }
}

// same, bf16 src -> bf16 dst (for V transpose); src stride lds_src, dst stride R
static __device__ __forceinline__ void tile64_b16(
    const __bf16* __restrict__ src, __bf16* __restrict__ dst,
    int src_ld, int dst_ld, int tid, __bf16* t /* [64*72] */)
{
    {
        const int r = tid >> 2, cq = (tid & 3) * 16;
        const __bf16* p = src + (size_t)r * src_ld + cq;
        union { uint4 u; __bf16 b[8]; } a0, a1;
        a0.u = *(const uint4*)(p);
        a1.u = *(const uint4*)(p + 8);
        #pragma unroll
        for (int e = 0; e < 8; ++e) {
            t[(cq + e) * 72 + r]     = a0.b[e];
            t[(cq + 8 + e) * 72 + r] = a1.b[e];
        }
    }
    __syncthreads();
    {
        const int c = tid >> 2, rq = (tid & 3) * 16;
        uint4 u0 = *(const uint4*)(&t[c * 72 + rq]);
        uint4 u1 = *(const uint4*)(&t[c * 72 + rq + 8]);
        __bf16* q = dst + (size_t)c * dst_ld + rq;
        *(uint4*)(q)     = u0;
        *(uint4*)(q + 8) = u1;
    }
}

// ---------------------------------------------------------------------------
// Fused prep: [0,2048) Wq-T; [2048,2560) Wk-T; [2560,3072) Wv-T;
// [3072,5120) x convert. 256 threads.
// ---------------------------------------------------------------------------
__global__ __launch_bounds__(256) void prep_kernel(
    const float* __restrict__ x,  __bf16* __restrict__ xb,
    const float* __restrict__ Wq, const float* __restrict__ Wk,
    const float* __restrict__ Wv, __bf16* __restrict__ Wt)
{
    __shared__ __bf16 t[64 * 72];
    const int bk  = blockIdx.x;
    const int tid = threadIdx.x;

    if (bk < 2048) {            // Wq [2048][4096] -> Wt[0..4096) rows
        int ct = bk & 63, rt = bk >> 6;
        tile64_f32(Wq, Wt, 2048, 4096, rt * 64, ct * 64, tid, t);
    } else if (bk < 2560) {     // Wk [2048][1024] -> Wt[4096..5120)
        int idx = bk - 2048, ct = idx & 15, rt = idx >> 4;
        tile64_f32(Wk, Wt + (size_t)4096 * 2048, 2048, 1024, rt * 64, ct * 64, tid, t);
    } else if (bk < 3072) {     // Wv [2048][1024] -> Wt[5120..6144)
        int idx = bk - 2560, ct = idx & 15, rt = idx >> 4;
        tile64_f32(Wv, Wt + (size_t)5120 * 2048, 2048, 1024, rt * 64, ct * 64, tid, t);
    } else {                    // x convert
        int idx = (bk - 3072) * 256 + tid;
        const float* p = x + (size_t)idx * 8;
        float4 f0 = *(const float4*)p;
        float4 f1 = *(const float4*)(p + 4);
        union { uint4 u; __bf16 b[8]; } o;
        o.b[0] = (__bf16)f0.x; o.b[1] = (__bf16)f0.y; o.b[2] = (__bf16)f0.z; o.b[3] = (__bf16)f0.w;
        o.b[4] = (__bf16)f1.x; o.b[5] = (__bf16)f1.y; o.b[6] = (__bf16)f1.z; o.b[7] = (__bf16)f1.w;
        *(uint4*)(xb + (size_t)idx * 8) = o.u;
    }
}

// ---------------------------------------------------------------------------
// Fused RoPE + V-transpose + Wo-transpose (post-GEMM1).
// [0,2560): rope; [2560,3072): vtrans; [3072,5120): Wo-T.
// ---------------------------------------------------------------------------
__global__ __launch_bounds__(256) void rope_vtrans_wot_kernel(
    __bf16* __restrict__ qkv, __bf16* __restrict__ vt,
    const float* __restrict__ Wo, __bf16* __restrict__ WoT)
{
    __shared__ __bf16 t[64 * 72];
    const int bk  = blockIdx.x;
    const int tid = threadIdx.x;

    if (bk < 2560) {
        int idx  = bk * 256 + tid;
        int part = idx & 7;
        int tt   = idx >> 3;
        int head = tt % 40;
        int row  = tt / 40;
        int n    = row & 1023;
        int col0 = (head < 32) ? head * 128 : 4096 + (head - 32) * 128;
        size_t base = (size_t)row * 6144 + col0 + part * 8;

        union { uint4 u; __bf16 b[8]; } x1, x2, o1, o2;
        x1.u = *(const uint4*)(qkv + base);
        x2.u = *(const uint4*)(qkv + base + 64);
        #pragma unroll
        for (int e = 0; e < 8; ++e) {
            int j = part * 8 + e;
            float inv_freq = exp2f(-(float)j * 0.20762050593046015f); // log2(1e4)/64
            float ang = (float)n * inv_freq;
            float sv, cv;
            __sincosf(ang, &sv, &cv);
            float a = (float)x1.b[e], b2 = (float)x2.b[e];
            o1.b[e] = (__bf16)(a * cv - b2 * sv);
            o2.b[e] = (__bf16)(a * sv + b2 * cv);
        }
        *(uint4*)(qkv + base)      = o1.u;
        *(uint4*)(qkv + base + 64) = o2.u;
    } else if (bk < 3072) {      // V cols of qkv -> vt[bh][128][1024]
        int idx = bk - 2560;     // 512: bh = idx>>5, rem 32 = 16 ktiles x 2 vtiles
        int bh = idx >> 5, rem = idx & 31;
        int k0 = (rem >> 1) * 64, v0 = (rem & 1) * 64;
        int b = bh >> 3, h = bh & 7;
        const __bf16* src = qkv + (size_t)(b * 1024 + k0) * 6144 + 5120 + h * 128 + v0;
        __bf16* dst = vt + ((size_t)bh * 128 + v0) * 1024 + k0;
        tile64_b16(src, dst, 6144, 1024, tid, t);
    } else {                     // Wo [4096][2048] -> WoT [2048][4096]
        int idx = bk - 3072;     // 2048: 32 ctiles x 64 rtiles
        int ct = idx & 31, rt = idx >> 5;
        tile64_f32(Wo, WoT, 4096, 2048, rt * 64, ct * 64, tid, t);
    }
}

// ---------------------------------------------------------------------------
// GEMM: C[z][M][N] = A[M][koff:] * Bt[N][koff:]^T, bf16, tile 128x128, BK=64.
// XOR-swizzled LDS, DMA staging. Split-K: koff = z*kc_base.
// (R0 structure: 256 thr / 4 waves, 32 KiB LDS -> 3 blocks/CU; cross-block
//  overlap of LDS-unit service and MFMA pipes is what 1-block/CU 256-tile
//  variants lost. Measured 61.5 us / MfmaUtil 34%.)
// ---------------------------------------------------------------------------
__global__ __launch_bounds__(256) void gemm_bt(
    const __bf16* __restrict__ A,
    const __bf16* __restrict__ Bt,
    __bf16* __restrict__ C,
    int M, int lda, int ldb, int ldc,
    int kc_base, int kc_extra)
{
    __shared__ __bf16 As[128 * 64];
    __shared__ __bf16 Bs[128 * 64];

    const int tid  = threadIdx.x;
    const int wave = tid >> 6;
    const int lane = tid & 63;
    const int quad = lane >> 4;
    const int l15  = lane & 15;
    const int wr   = wave >> 1, wc = wave & 1;

    const int bm = blockIdx.y * 128;
    const int bn = blockIdx.x * 128;
    const int z  = blockIdx.z;
    const int Kc = kc_base + ((z == (int)gridDim.z - 1) ? kc_extra : 0);

    A  += (size_t)z * kc_base;
    Bt += (size_t)z * kc_base;
    C  += (size_t)z * M * ldc;

    floatx4 acc[16];
    #pragma unroll
    for (int i = 0; i < 16; ++i) acc[i] = floatx4{0.f, 0.f, 0.f, 0.f};

    const int sr = lane >> 3;
    const int sc = ((lane & 7) ^ sr) * 8;
    const __bf16* a0 = A  + (size_t)(bm + wave * 32 + sr) * lda + sc;
    const __bf16* b0 = Bt + (size_t)(bn + wave * 32 + sr) * ldb + sc;
    __bf16* asd = As + (wave * 32) * 64;
    __bf16* bsd = Bs + (wave * 32) * 64;

    for (int k0 = 0; k0 < Kc; k0 += 64) {
        __syncthreads();
        #pragma unroll
        for (int r = 0; r < 4; ++r) {
            async_cp16(a0 + (size_t)(r * 8) * lda + k0, asd + (r * 8) * 64);
            async_cp16(b0 + (size_t)(r * 8) * ldb + k0, bsd + (r * 8) * 64);
        }
        __syncthreads();

        #pragma unroll
        for (int ko = 0; ko < 2; ++ko) {
            bf16x8 af[4], bf[4];
            #pragma unroll
            for (int t = 0; t < 4; ++t)
                af[t] = *(const bf16x8*)(
                    &As[(wr * 64 + t * 16 + l15) * 64 + (((ko * 4 + quad) ^ (l15 & 7)) * 8)]);
            #pragma unroll
            for (int u = 0; u < 4; ++u)
                bf[u] = *(const bf16x8*)(
                    &Bs[(wc * 64 + u * 16 + l15) * 64 + (((ko * 4 + quad) ^ (l15 & 7)) * 8)]);
            #pragma unroll
            for (int t = 0; t < 4; ++t)
                #pragma unroll
                for (int u = 0; u < 4; ++u)
                    acc[t * 4 + u] = __builtin_amdgcn_mfma_f32_16x16x32_bf16(
                        af[t], bf[u], acc[t * 4 + u], 0, 0, 0);
        }
    }

    #pragma unroll
    for (int t = 0; t < 4; ++t)
        #pragma unroll
        for (int u = 0; u < 4; ++u)
            #pragma unroll
            for (int r = 0; r < 4; ++r) {
                int row = bm + wr * 64 + t * 16 + quad * 4 + r;
                int col = bn + wc * 64 + u * 16 + l15;
                C[(size_t)row * ldc + col] = (__bf16)acc[t * 4 + u][r];
            }
}

// ---------------------------------------------------------------------------
// Split-K reduce: out = sum of 3 bf16 partials, fp32 out.
// ---------------------------------------------------------------------------
__global__ __launch_bounds__(256) void reduce_kernel(
    const __bf16* __restrict__ part, float* __restrict__ out)
{
    int idx = blockIdx.x * 256 + threadIdx.x;
    const size_t S = (size_t)2048 * 2048;
    union { uint4 u; __bf16 b[8]; } p0, p1, p2;
    p0.u = *(const uint4*)(part + (size_t)idx * 8);
    p1.u = *(const uint4*)(part + S + (size_t)idx * 8);
    p2.u = *(const uint4*)(part + 2 * S + (size_t)idx * 8);
    float4 o0, o1;
    o0.x = (float)p0.b[0] + (float)p1.b[0] + (float)p2.b[0];
    o0.y = (float)p0.b[1] + (float)p1.b[1] + (float)p2.b[1];
    o0.z = (float)p0.b[2] + (float)p1.b[2] + (float)p2.b[2];
    o0.w = (float)p0.b[3] + (float)p1.b[3] + (float)p2.b[3];
    o1.x = (float)p0.b[4] + (float)p1.b[4] + (float)p2.b[4];
    o1.y = (float)p0.b[5] + (float)p1.b[5] + (float)p2.b[5];
    o1.z = (float)p0.b[6] + (float)p1.b[6] + (float)p2.b[6];
    o1.w = (float)p0.b[7] + (float)p1.b[7] + (float)p2.b[7];
    *(float4*)(out + (size_t)idx * 8)     = o0;
    *(float4*)(out + (size_t)idx * 8 + 4) = o1;
}

// ---------------------------------------------------------------------------
// Causal flash attention (R5 structure: balanced pairing, max-free softmax,
// swizzled staging). T14 register-prefetch: K/V tile t+1 is loaded into VGPRs
// while tile t computes; ds_write at top of next iteration. Removes the
// per-tile exposed global->LDS latency of the old DMA+drain pattern.
// ---------------------------------------------------------------------------
__global__ __launch_bounds__(512, 2) void attn_kernel(
    const __bf16* __restrict__ qkv,
    const __bf16* __restrict__ vt,
    __bf16* __restrict__ ao)
{
    const int PS_LD = 72;
    __shared__ __bf16 Ks[64 * 128];      // [key][kdim], swizzled
    __shared__ __bf16 Vs[128 * 64];      // [vdim][key], swizzled
    __shared__ __bf16 Ps[8][16 * PS_LD]; // per-wave [qrow][key], padded

    const int tid  = threadIdx.x;
    const int wave = tid >> 6;
    const int lane = tid & 63;
    const int quad = lane >> 4;
    const int l15  = lane & 15;
    const int i    = wave >> 1;
    const int rt   = wave & 1;

    const int pair = blockIdx.x;
    const int bh   = blockIdx.y;
    const int b    = bh >> 3, h = bh & 7;
    const __bf16* vtb = vt + (size_t)bh * 128 * 1024;

    const int keyA = wave * 8 + (lane >> 4);
    const int keyB = keyA + 4;
    const int chA  = (lane & 15) ^ (keyA & 15);
    const int chB  = (lane & 15) ^ (keyB & 15);
    const __bf16* gK0 = qkv + (size_t)(b * 1024 + keyA) * 6144 + 4096 + h * 128 + chA * 8;
    const __bf16* gK1 = qkv + (size_t)(b * 1024 + keyB) * 6144 + 4096 + h * 128 + chB * 8;
    __bf16* lK0 = Ks + (wave * 8) * 128;
    __bf16* lK1 = Ks + (wave * 8 + 4) * 128;

    const int vdA = wave * 16 + (lane >> 3);
    const int vdB = vdA + 8;
    const int cvA = (lane & 7) ^ (vdA & 7);
    const int cvB = (lane & 7) ^ (vdB & 7);
    const __bf16* gV0 = vtb + (size_t)vdA * 1024 + cvA * 8;
    const __bf16* gV1 = vtb + (size_t)vdB * 1024 + cvB * 8;
    __bf16* lV0 = Vs + (wave * 16) * 64;
    __bf16* lV1 = Vs + (wave * 16 + 8) * 64;

    bf16x8 onesf;
    #pragma unroll
    for (int j = 0; j < 8; ++j) onesf[j] = (__bf16)1.0f;

    const float C2 = 0.12751898549f;   // (1/sqrt(128)) * log2(e)

    #pragma unroll
    for (int ph = 0; ph < 2; ++ph) {
        const int qt    = ph ? (31 - pair) : pair;
        const int qrow0 = qt * 32 + rt * 16;

        const __bf16* qp = qkv + (size_t)(b * 1024 + qrow0 + l15) * 6144 + (h * 4 + i) * 128;
        bf16x8 qf[4];
        #pragma unroll
        for (int c = 0; c < 4; ++c)
            qf[c] = *(const bf16x8*)(qp + c * 32 + quad * 8);

        floatx4 acc[8];
        #pragma unroll
        for (int u = 0; u < 8; ++u) acc[u] = floatx4{0.f, 0.f, 0.f, 0.f};
        floatx4 accl = floatx4{0.f, 0.f, 0.f, 0.f};

        const int ntiles = (qt >> 1) + 1;

        // ---- prologue: load K/V tile 0 into regs ----
        uint4 rk0 = *(const uint4*)(gK0);
        uint4 rk1 = *(const uint4*)(gK1);
        uint4 rv0 = *(const uint4*)(gV0);
        uint4 rv1 = *(const uint4*)(gV1);

        for (int t = 0; t < ntiles; ++t) {
            const int kt = t * 64;
            __syncthreads();                       // tile t-1 reads complete
            // stage tile t regs -> LDS (layout identical to old DMA path)
            *(uint4*)(lK0 + lane * 8) = rk0;
            *(uint4*)(lK1 + lane * 8) = rk1;
            *(uint4*)(lV0 + lane * 8) = rv0;
            *(uint4*)(lV1 + lane * 8) = rv1;
            // issue loads for tile t+1 (latency hides under compute of t)
            if (t + 1 < ntiles) {
                const int kt1 = kt + 64;
                rk0 = *(const uint4*)(gK0 + (size_t)kt1 * 6144);
                rk1 = *(const uint4*)(gK1 + (size_t)kt1 * 6144);
                rv0 = *(const uint4*)(gV0 + kt1);
                rv1 = *(const uint4*)(gV1 + kt1);
            }
            __syncthreads();                       // tile t visible

            floatx4 s[4];
            #pragma unroll
            for (int ks = 0; ks < 4; ++ks) s[ks] = floatx4{0.f, 0.f, 0.f, 0.f};
            #pragma unroll
            for (int c = 0; c < 4; ++c) {
                #pragma unroll
                for (int ks = 0; ks < 4; ++ks) {
                    bf16x8 kf = *(const bf16x8*)(
                        &Ks[(ks * 16 + l15) * 128 + ((c * 4 + quad) ^ l15) * 8]);
                    s[ks] = __builtin_amdgcn_mfma_f32_16x16x32_bf16(qf[c], kf, s[ks], 0, 0, 0);
                }
            }

            #pragma unroll
            for (int r = 0; r < 4; ++r) {
                int qrow = qrow0 + quad * 4 + r;
                #pragma unroll
                for (int ks = 0; ks < 4; ++ks) {
                    int kc = kt + ks * 16 + l15;
                    float p = (kc <= qrow) ? exp2f(s[ks][r] * C2) : 0.0f;
                    Ps[wave][(quad * 4 + r) * PS_LD + ks * 16 + l15] = (__bf16)p;
                }
            }

            #pragma unroll
            for (int s2 = 0; s2 < 2; ++s2) {
                bf16x8 pa = *(const bf16x8*)(&Ps[wave][l15 * PS_LD + s2 * 32 + quad * 8]);
                accl = __builtin_amdgcn_mfma_f32_16x16x32_bf16(pa, onesf, accl, 0, 0, 0);
                #pragma unroll
                for (int u = 0; u < 8; ++u) {
                    bf16x8 vf = *(const bf16x8*)(
                        &Vs[(u * 16 + l15) * 64 + (((s2 * 4 + quad) ^ (l15 & 7))) * 8]);
                    acc[u] = __builtin_amdgcn_mfma_f32_16x16x32_bf16(pa, vf, acc[u], 0, 0, 0);
                }
            }
        }

        #pragma unroll
        for (int r = 0; r < 4; ++r) {
            float inv = 1.0f / accl[r];
            int row = qrow0 + quad * 4 + r;
            __bf16* op = ao + (size_t)(b * 1024 + row) * 4096 + (h * 4 + i) * 128;
            #pragma unroll
            for (int u = 0; u < 8; ++u)
                op[u * 16 + l15] = (__bf16)(acc[u][r] * inv);
        }
    }
}

// ---------------------------------------------------------------------------
extern "C" void kernel_launch(void* const* d_in, const int* in_sizes, int n_in,
                              void* d_out, int out_size, void* d_ws, size_t ws_size,
                              hipStream_t stream)
{
    const float* x  = (const float*)d_in[0];   // [2048][2048]
    const float* Wq = (const float*)d_in[1];   // [2048][4096]
    const float* Wk = (const float*)d_in[2];   // [2048][1024]
    const float* Wv = (const float*)d_in[3];   // [2048][1024]
    const float* Wo = (const float*)d_in[4];   // [4096][2048]
    float* out = (float*)d_out;                // [2048][2048]

    const size_t MB = 1024 * 1024;
    char* ws = (char*)d_ws;                    // 60 MB total
    __bf16* qkv  = (__bf16*)(ws);              // [2048][6144]    0-24  (dead after attn)
    __bf16* vtb  = (__bf16*)(ws + 24 * MB);    // [16][128][1024] 24-28 (dead after attn)
    __bf16* xb   = (__bf16*)(ws + 28 * MB);    // [2048][2048]    28-36 (dead after GEMM1)
    __bf16* Wt   = (__bf16*)(ws + 36 * MB);    // [6144][2048]    36-60 (dead after GEMM1)
    __bf16* WoT  = (__bf16*)(ws + 28 * MB);    // [2048][4096]    28-44 (post-GEMM1)
    __bf16* ao   = (__bf16*)(ws + 44 * MB);    // [2048][4096]    44-60 (post-GEMM1)
    __bf16* part = (__bf16*)(ws);              // [3][2048][2048] 0-24  (post-attn)

    // 1) prep: transpose Wq/Wk/Wv (vectorized 64x64 tiles) + convert x
    prep_kernel<<<5120, 256, 0, stream>>>(x, xb, Wq, Wk, Wv, Wt);
    // 2) fused QKV projection: qkv[2048][6144]
    gemm_bt<<<dim3(48, 16), 256, 0, stream>>>(xb, Wt, qkv, 2048, 2048, 2048, 6144, 2048, 0);
    // 3) RoPE + V transpose + Wo transpose (WoT overwrites xb/Wt head)
    rope_vtrans_wot_kernel<<<5120, 256, 0, stream>>>(qkv, vtb, Wo, WoT);
    // 4) attention (writes ao; qkv/vtb dead afterwards)
    attn_kernel<<<dim3(16, 16), 512, 0, stream>>>(qkv, vtb, ao);
    // 5) output projection, split-K=3 (1344/1344/1408), partials in dead qkv
    gemm_bt<<<dim3(16, 16, 3), 256, 0, stream>>>(ao, WoT, part, 2048, 4096, 4096, 2048, 1344, 64);
    // 6) reduce partials -> fp32 out
    reduce_kernel<<<2048, 256, 0, stream>>>(part, out);
}